// Round 4
// baseline (4381.129 us; speedup 1.0000x reference)
//
#include <hip/hip_runtime.h>
#include <math.h>

#define NMODES 4096
#define TPB    256

// One block per FFT-ordered output mode idx: k = idx (idx < N/2) else idx - N.
// f[idx] = sum_j (vre[j] + i*vim[j]) * exp(+i * k * x_j).
// Output layout is runtime-adaptive (harness flattens complex64 via float32):
//   out_size == 4096  -> out[idx] = Re f[idx]                (astype: real only)
//   out_size == 8192  -> out[idx] = Re f[idx], out[4096+idx] = Im f[idx] (planar)
__global__ __launch_bounds__(TPB) void nufft_ref(
    const float* __restrict__ pts, const float* __restrict__ vre,
    const float* __restrict__ vim, float* __restrict__ out, int M, int out_size)
{
    const int idx = blockIdx.x;                      // 0..NMODES-1, FFT order
    const int k   = (idx < NMODES / 2) ? idx : idx - NMODES;
    const float kf = (float)k;
    const int tid = threadIdx.x;

    float sre = 0.f, sim = 0.f;
    for (int j = tid; j < M; j += TPB) {
        float x  = pts[j];
        float cr = vre[j];
        float ci = vim[j];
        float s, c;
        sincosf(kf * x, &s, &c);                     // exp(i*k*x) = c + i*s
        sre += fmaf(cr, c, -(ci * s));               // cr*c - ci*s
        sim += fmaf(cr, s,   ci * c );               // cr*s + ci*c
    }

    __shared__ float red_re[TPB];
    __shared__ float red_im[TPB];
    red_re[tid] = sre;
    red_im[tid] = sim;
    __syncthreads();
    for (int off = TPB / 2; off > 0; off >>= 1) {
        if (tid < off) {
            red_re[tid] += red_re[tid + off];
            red_im[tid] += red_im[tid + off];
        }
        __syncthreads();
    }
    if (tid == 0) {
        if (out_size >= 2 * NMODES) {
            out[idx]          = red_re[0];           // planar: Re block
            out[NMODES + idx] = red_im[0];           // planar: Im block
        } else {
            out[idx] = red_re[0];                    // real part only
        }
    }
}

extern "C" void kernel_launch(void* const* d_in, const int* in_sizes, int n_in,
                              void* d_out, int out_size, void* d_ws, size_t ws_size,
                              hipStream_t stream)
{
    const float* pts = (const float*)d_in[0];
    const float* vre = (const float*)d_in[1];
    const float* vim = (const float*)d_in[2];
    float* out = (float*)d_out;
    const int M = in_sizes[0];

    hipLaunchKernelGGL(nufft_ref, dim3(NMODES), dim3(TPB), 0, stream,
                       pts, vre, vim, out, M, out_size);
}

// Round 5
// 722.980 us; speedup vs baseline: 6.0598x; 6.0598x over previous
//
#include <hip/hip_runtime.h>
#include <math.h>

#define NMODES 4096
#define HALF   2048
#define KPT    8
#define TPB    256
#define TILE   256

// hw trig: v_sin_f32/v_cos_f32 compute sin/cos(S0 * 2*pi) — input in REVOLUTIONS.
__device__ __forceinline__ float sin2pi(float r) {
    float o; asm volatile("v_sin_f32 %0, %1" : "=v"(o) : "v"(r)); return o;
}
__device__ __forceinline__ float cos2pi(float r) {
    float o; asm volatile("v_cos_f32 %0, %1" : "=v"(o) : "v"(r)); return o;
}

// Each block processes points [b*ppb, b*ppb+ppb); thread t owns positive modes
// kp = 8t .. 8t+7; +/-k pairing yields k=-kp for free. tid 255 also owns kp=2048.
// Partial spectra go to ws in PLANAR layout: buf[0:4096]=Re, buf[4096:8192]=Im.
__global__ __launch_bounds__(TPB) void nufft_partial(
    const float* __restrict__ pts, const float* __restrict__ vre,
    const float* __restrict__ vim, float* __restrict__ ws, int M, int ppb)
{
    __shared__ float4 sA[TILE];   // {x_rev, cos(x), sin(x), cr}
    __shared__ float  sCi[TILE];

    const int tid = threadIdx.x;
    const int b   = blockIdx.x;
    const int j0  = b * ppb;
    const float k0f = (float)(tid * KPT);
    const float inv2pi = 0.15915494309189535f;

    float arr[KPT], aii[KPT], ari[KPT], air[KPT];
#pragma unroll
    for (int t = 0; t < KPT; ++t) { arr[t] = 0.f; aii[t] = 0.f; ari[t] = 0.f; air[t] = 0.f; }
    float xrr = 0.f, xii = 0.f, xri = 0.f, xir = 0.f;   // kp=2048 (tid 255 only)

    for (int base = 0; base < ppb; base += TILE) {
        // ---- stage one tile of points into LDS ----
        int j = j0 + base + tid;
        float x = 0.f, cr = 0.f, ci = 0.f;
        if (j < M) { x = pts[j]; cr = vre[j]; ci = vim[j]; }
        float sn, cs;
        sincosf(x, &sn, &cs);         // libm, radians: recurrence constants
        float xr = x * inv2pi;
        xr -= rintf(xr);              // revolutions in [-0.5, 0.5]
        __syncthreads();
        sA[tid]  = make_float4(xr, cs, sn, cr);
        sCi[tid] = ci;
        __syncthreads();

        // ---- accumulate over staged points ----
        for (int p = 0; p < TILE; ++p) {
            float4 v   = sA[p];           // broadcast ds_read_b128
            float ci_p = sCi[p];
            float xr_p = v.x, cs_p = v.y, sn_p = v.z, cr_p = v.w;

            // seed e_{k0}: exact mod-1 reduction in revolutions, then hw trig
            float a0 = k0f * xr_p;
            a0 -= rintf(a0);              // [-0.5, 0.5] revolutions
            float er = cos2pi(a0);
            float ei = sin2pi(a0);
            // e_{k0-1} = e_{k0} * (cos - i sin)
            float pr  = fmaf(er, cs_p,  ei * sn_p);
            float pim = fmaf(ei, cs_p, -(er * sn_p));
            float twoc = cs_p + cs_p;

#pragma unroll
            for (int t = 0; t < KPT; ++t) {
                arr[t] = fmaf(cr_p, er, arr[t]);
                aii[t] = fmaf(ci_p, ei, aii[t]);
                ari[t] = fmaf(cr_p, ei, ari[t]);
                air[t] = fmaf(ci_p, er, air[t]);
                // Chebyshev advance: e_{k+1} = 2cos(x)*e_k - e_{k-1}
                float nr = fmaf(twoc, er, -pr);
                float ni = fmaf(twoc, ei, -pim);
                pr = er; pim = ei; er = nr; ei = ni;
            }
            if (tid == TPB - 1) {         // er,ei now hold e_{2048}
                xrr = fmaf(cr_p, er, xrr);
                xii = fmaf(ci_p, ei, xii);
                xri = fmaf(cr_p, ei, xri);
                xir = fmaf(ci_p, er, xir);
            }
        }
    }

    // ---- planar partial spectrum: Re in [0,4096), Im in [4096,8192) ----
    float* buf = ws + (size_t)b * (2 * NMODES);
#pragma unroll
    for (int t = 0; t < KPT; ++t) {
        int kp = tid * KPT + t;
        buf[kp]          = arr[t] - aii[t];    // Re f[+kp]
        buf[NMODES + kp] = ari[t] + air[t];    // Im f[+kp]
        if (kp > 0) {
            int idx = NMODES - kp;             // k = -kp
            buf[idx]          = arr[t] + aii[t];
            buf[NMODES + idx] = air[t] - ari[t];
        }
    }
    if (tid == TPB - 1) {                      // k = -2048 at index 2048
        buf[HALF]          = xrr + xii;
        buf[NMODES + HALF] = xir - xri;
    }
}

// out[i] = sum_b ws[b*8192 + i]. Planar partials make real-only (out_size=4096)
// and planar (out_size=8192) layouts use identical indexing.
__global__ __launch_bounds__(256) void nufft_reduce(
    const float* __restrict__ ws, float* __restrict__ out, int nb, int out_size)
{
    int i = blockIdx.x * blockDim.x + threadIdx.x;
    if (i >= out_size) return;
    float s = 0.f;
    for (int b = 0; b < nb; ++b) s += ws[(size_t)b * (2 * NMODES) + i];
    out[i] = s;   // fully overwrites d_out (poison-safe)
}

extern "C" void kernel_launch(void* const* d_in, const int* in_sizes, int n_in,
                              void* d_out, int out_size, void* d_ws, size_t ws_size,
                              hipStream_t stream)
{
    const float* pts = (const float*)d_in[0];
    const float* vre = (const float*)d_in[1];
    const float* vim = (const float*)d_in[2];
    float* out = (float*)d_out;
    float* ws  = (float*)d_ws;
    const int M = in_sizes[0];

    int nb = 1024;
    while (nb > 1 && (size_t)nb * (2 * NMODES) * sizeof(float) > ws_size) nb >>= 1;
    int ppb = (M + nb - 1) / nb;
    ppb = ((ppb + TILE - 1) / TILE) * TILE;

    int osz = out_size;
    if (osz > 2 * NMODES) osz = 2 * NMODES;

    hipLaunchKernelGGL(nufft_partial, dim3(nb), dim3(TPB), 0, stream,
                       pts, vre, vim, ws, M, ppb);
    hipLaunchKernelGGL(nufft_reduce, dim3((osz + 255) / 256), dim3(256), 0, stream,
                       ws, out, nb, osz);
}

// Round 6
// 180.752 us; speedup vs baseline: 24.2383x; 3.9998x over previous
//
#include <hip/hip_runtime.h>
#include <math.h>

#define NM    4096          // output modes
#define HALFN 2048
#define MR    8192          // oversampled grid (2x)
#define MRM   (MR - 1)
#define STPB  512           // spread threads per block

// hw trig: v_sin_f32/v_cos_f32 take REVOLUTIONS (sin/cos of 2*pi*r). Verified round 5.
__device__ __forceinline__ float sin2pi(float r) {
    float o; asm volatile("v_sin_f32 %0, %1" : "=v"(o) : "v"(r)); return o;
}
__device__ __forceinline__ float cos2pi(float r) {
    float o; asm volatile("v_cos_f32 %0, %1" : "=v"(o) : "v"(r)); return o;
}

// ---------------- 1) spread: points -> privatized LDS grid -> ws partials ----
// b_m = sum_j c_j * exp(-alpha*(m - p_j)^2), p_j = x_j/gamma (grid units), 8-wide.
// ws layout (floats): [0,16384) = reduced grid G (re|im planar),
//                     [16384 + b*16384, ...) = block b's partial grid.
__global__ __launch_bounds__(STPB) void nufft_spread(
    const float* __restrict__ pts, const float* __restrict__ vre,
    const float* __restrict__ vim, float* __restrict__ ws,
    int M, int ppb, float nalpha)
{
    __shared__ __align__(16) float gre[MR];
    __shared__ __align__(16) float gim[MR];
    const int tid = threadIdx.x;
    const int b   = blockIdx.x;

    for (int i = tid; i < MR; i += STPB) { gre[i] = 0.f; gim[i] = 0.f; }
    __syncthreads();

    const int j0   = b * ppb;
    const int jend = min(j0 + ppb, M);
    const float inv2pi = 0.15915494309189535f;

    for (int j = j0 + tid; j < jend; j += STPB) {
        float x  = pts[j];
        float cr = vre[j];
        float ci = vim[j];
        float u = x * inv2pi;
        u -= floorf(u);                 // [0,1)
        float p  = u * (float)MR;       // grid position [0, 8192]
        float fl = floorf(p);
        int   i0 = (int)fl - 3;
        float d  = fl - p - 3.0f;       // m - p for m = i0, in (-4, -3]
#pragma unroll
        for (int i = 0; i < 8; ++i) {
            float wgt = exp2f(nalpha * d * d);    // exp(-alpha*d^2)
            int m = (i0 + i) & MRM;
            atomicAdd(&gre[m], wgt * cr);
            atomicAdd(&gim[m], wgt * ci);
            d += 1.0f;
        }
    }
    __syncthreads();

    float4* buf = (float4*)(ws + 16384 + (size_t)b * 16384);
    const float4* g4r = (const float4*)gre;
    const float4* g4i = (const float4*)gim;
    for (int i = tid; i < MR / 4; i += STPB) {
        buf[i]          = g4r[i];
        buf[MR / 4 + i] = g4i[i];
    }
}

// ---------------- 2) reduce partial grids -> G ------------------------------
__global__ __launch_bounds__(256) void nufft_reduce_grid(
    const float* __restrict__ ws, int nb)
{
    int i = blockIdx.x * 256 + threadIdx.x;          // float4 index < 4096
    if (i >= 4096) return;
    const float4* src = (const float4*)(ws + 16384);
    float4 s = make_float4(0.f, 0.f, 0.f, 0.f);
    for (int b = 0; b < nb; ++b) {
        float4 v = src[(size_t)b * 4096 + i];
        s.x += v.x; s.y += v.y; s.z += v.z; s.w += v.w;
    }
    ((float4*)ws)[i] = s;
}

// ---------------- 3) single-block 8192-pt FFT (+i sign) + deconv + output ---
// B_k = sum_m b_m e^{+2pi i k m / MR};  f[k] = B_k * sfac * e^{k^2 tau}.
__global__ __launch_bounds__(1024) void nufft_fft(
    const float* __restrict__ ws, float* __restrict__ out,
    int out_size, float sfac, float taul2e)
{
    __shared__ float re[MR];
    __shared__ float im[MR];
    const int tid = threadIdx.x;

    // load with bit-reversal (13-bit)
    for (int q = tid; q < MR; q += 1024) {
        int r = __brev((unsigned)q) >> 19;
        re[r] = ws[q];
        im[r] = ws[MR + q];
    }
    __syncthreads();

    for (int half = 1; half < MR; half <<= 1) {
        int len = half << 1;
        float sc = 1.0f / (float)len;
        for (int q = tid; q < MR / 2; q += 1024) {
            int t  = q & (half - 1);
            int i0 = ((q - t) << 1) + t;             // (q/half)*len + t
            float tf = (float)t * sc;                // t/len in [0, 0.5)
            float wr = cos2pi(tf);
            float wi = sin2pi(tf);                   // e^{+2pi i t/len}
            float ur = re[i0],        ui = im[i0];
            float xr = re[i0 + half], xi = im[i0 + half];
            float vr = fmaf(xr, wr, -(xi * wi));
            float vi = fmaf(xr, wi,   xi * wr);
            re[i0]        = ur + vr;  im[i0]        = ui + vi;
            re[i0 + half] = ur - vr;  im[i0 + half] = ui - vi;
        }
        __syncthreads();
    }

    // deconvolve + write planar (or real-only) FFT-ordered modes
    for (int idx = tid; idx < NM; idx += 1024) {
        int k    = (idx < HALFN) ? idx : idx - NM;
        int src  = (idx < HALFN) ? idx : idx + NM;   // k mod 8192
        float kk = (float)k;
        float corr = sfac * exp2f(kk * kk * taul2e); // sfac * e^{k^2 tau}
        float fre = re[src] * corr;
        float fim = im[src] * corr;
        if (out_size >= 2 * NM) {
            out[idx]      = fre;
            out[NM + idx] = fim;
        } else {
            out[idx] = fre;
        }
    }
}

extern "C" void kernel_launch(void* const* d_in, const int* in_sizes, int n_in,
                              void* d_out, int out_size, void* d_ws, size_t ws_size,
                              hipStream_t stream)
{
    const float* pts = (const float*)d_in[0];
    const float* vre = (const float*)d_in[1];
    const float* vim = (const float*)d_in[2];
    float* out = (float*)d_out;
    float* ws  = (float*)d_ws;
    const int M = in_sizes[0];

    // Gaussian kernel parameters (double-derived, balanced truncation/aliasing)
    const double PI  = 3.14159265358979323846;
    const double gam = 2.0 * PI / (double)MR;
    const double dif = (double)(MR - HALFN) * (MR - HALFN) - (double)HALFN * HALFN;
    const double tau = (4.0 * gam) / (2.0 * sqrt(dif));        // P=4 balance
    const double alpha = gam * gam / (4.0 * tau);
    const double L2E = 1.4426950408889634;
    const float nalpha = (float)(-alpha * L2E);                // exp2 scale
    const float sfac   = (float)(gam / sqrt(4.0 * PI * tau));
    const float taul2e = (float)(tau * L2E);

    int nb = (int)(ws_size / 65536) - 1;   // 64 KB per partial grid + 64 KB for G
    if (nb > 255) nb = 255;
    if (nb < 1)   nb = 1;
    int ppb = (M + nb - 1) / nb;

    hipLaunchKernelGGL(nufft_spread, dim3(nb), dim3(STPB), 0, stream,
                       pts, vre, vim, ws, M, ppb, nalpha);
    hipLaunchKernelGGL(nufft_reduce_grid, dim3(16), dim3(256), 0, stream, ws, nb);
    hipLaunchKernelGGL(nufft_fft, dim3(1), dim3(1024), 0, stream,
                       ws, out, out_size, sfac, taul2e);
}

// Round 7
// 156.649 us; speedup vs baseline: 27.9677x; 1.1539x over previous
//
#include <hip/hip_runtime.h>
#include <math.h>

#define NM    4096          // output modes
#define HALFN 2048
#define MR    8192          // oversampled grid (2x)
#define MRM   (MR - 1)
#define STPB  512           // spread threads per block
#define NBMAX 511           // partial grids (511+1 reduced = 512*64KB = 33.55MB)

// hw trig: v_sin_f32/v_cos_f32 take REVOLUTIONS (sin/cos of 2*pi*r). Verified round 5.
__device__ __forceinline__ float sin2pi(float r) {
    float o; asm volatile("v_sin_f32 %0, %1" : "=v"(o) : "v"(r)); return o;
}
__device__ __forceinline__ float cos2pi(float r) {
    float o; asm volatile("v_cos_f32 %0, %1" : "=v"(o) : "v"(r)); return o;
}

// ---------------- 1) spread: points -> privatized LDS grid -> ws partials ----
// b_m = sum_j c_j * exp(-alpha*(m - p_j)^2), p_j = x_j/gamma (grid units), 8-wide.
// ws layout (floats): [0,16384) = reduced grid G (re|im planar),
//                     [16384 + b*16384, ...) = block b's partial grid.
__global__ __launch_bounds__(STPB) void nufft_spread(
    const float* __restrict__ pts, const float* __restrict__ vre,
    const float* __restrict__ vim, float* __restrict__ ws,
    int M, int ppb, float nalpha)
{
    __shared__ __align__(16) float gre[MR];
    __shared__ __align__(16) float gim[MR];
    const int tid = threadIdx.x;
    const int b   = blockIdx.x;

    for (int i = tid; i < MR; i += STPB) { gre[i] = 0.f; gim[i] = 0.f; }
    __syncthreads();

    const int j0   = b * ppb;
    const int jend = min(j0 + ppb, M);
    const float inv2pi = 0.15915494309189535f;

#pragma unroll 2
    for (int j = j0 + tid; j < jend; j += STPB) {
        float x  = pts[j];
        float cr = vre[j];
        float ci = vim[j];
        float u = x * inv2pi;
        u -= floorf(u);                 // [0,1)
        float p  = u * (float)MR;       // grid position [0, 8192]
        float fl = floorf(p);
        int   i0 = (int)fl - 3;
        float d  = fl - p - 3.0f;       // m - p for m = i0, in (-4, -3]
#pragma unroll
        for (int i = 0; i < 8; ++i) {
            float wgt = exp2f(nalpha * d * d);    // exp(-alpha*d^2)
            int m = (i0 + i) & MRM;
            atomicAdd(&gre[m], wgt * cr);
            atomicAdd(&gim[m], wgt * ci);
            d += 1.0f;
        }
    }
    __syncthreads();

    float4* buf = (float4*)(ws + 16384 + (size_t)b * 16384);
    const float4* g4r = (const float4*)gre;
    const float4* g4i = (const float4*)gim;
    for (int i = tid; i < MR / 4; i += STPB) {
        buf[i]          = g4r[i];
        buf[MR / 4 + i] = g4i[i];
    }
}

// ---------------- 2) reduce partial grids -> G ------------------------------
// 128 blocks x 128 threads = 16384 threads: one float column per thread,
// coalesced 64KB sweeps per iteration, unrolled for outstanding loads.
__global__ __launch_bounds__(128) void nufft_reduce_grid(
    float* __restrict__ ws, int nb)
{
    int i = blockIdx.x * 128 + threadIdx.x;          // [0, 16384)
    const float* src = ws + 16384 + i;
    float s = 0.f;
#pragma unroll 8
    for (int b = 0; b < nb; ++b) s += src[(size_t)b * 16384];
    ws[i] = s;   // [0,16384) never aliases the read region
}

// ---------------- 3) single-block 8192-pt FFT (+i sign) + deconv + output ---
// B_k = sum_m b_m e^{+2pi i k m / MR};  f[k] = B_k * sfac * e^{k^2 tau}.
__global__ __launch_bounds__(1024) void nufft_fft(
    const float* __restrict__ ws, float* __restrict__ out,
    int out_size, float sfac, float taul2e)
{
    __shared__ float re[MR];
    __shared__ float im[MR];
    const int tid = threadIdx.x;

    // load with bit-reversal (13-bit)
    for (int q = tid; q < MR; q += 1024) {
        int r = __brev((unsigned)q) >> 19;
        re[r] = ws[q];
        im[r] = ws[MR + q];
    }
    __syncthreads();

    for (int half = 1; half < MR; half <<= 1) {
        int len = half << 1;
        float sc = 1.0f / (float)len;
        for (int q = tid; q < MR / 2; q += 1024) {
            int t  = q & (half - 1);
            int i0 = ((q - t) << 1) + t;             // (q/half)*len + t
            float tf = (float)t * sc;                // t/len in [0, 0.5)
            float wr = cos2pi(tf);
            float wi = sin2pi(tf);                   // e^{+2pi i t/len}
            float ur = re[i0],        ui = im[i0];
            float xr = re[i0 + half], xi = im[i0 + half];
            float vr = fmaf(xr, wr, -(xi * wi));
            float vi = fmaf(xr, wi,   xi * wr);
            re[i0]        = ur + vr;  im[i0]        = ui + vi;
            re[i0 + half] = ur - vr;  im[i0 + half] = ui - vi;
        }
        __syncthreads();
    }

    // deconvolve + write planar (or real-only) FFT-ordered modes
    for (int idx = tid; idx < NM; idx += 1024) {
        int k    = (idx < HALFN) ? idx : idx - NM;
        int src  = (idx < HALFN) ? idx : idx + NM;   // k mod 8192
        float kk = (float)k;
        float corr = sfac * exp2f(kk * kk * taul2e); // sfac * e^{k^2 tau}
        float fre = re[src] * corr;
        float fim = im[src] * corr;
        if (out_size >= 2 * NM) {
            out[idx]      = fre;
            out[NM + idx] = fim;
        } else {
            out[idx] = fre;
        }
    }
}

extern "C" void kernel_launch(void* const* d_in, const int* in_sizes, int n_in,
                              void* d_out, int out_size, void* d_ws, size_t ws_size,
                              hipStream_t stream)
{
    const float* pts = (const float*)d_in[0];
    const float* vre = (const float*)d_in[1];
    const float* vim = (const float*)d_in[2];
    float* out = (float*)d_out;
    float* ws  = (float*)d_ws;
    const int M = in_sizes[0];

    // Gaussian kernel parameters (double-derived, balanced truncation/aliasing)
    const double PI  = 3.14159265358979323846;
    const double gam = 2.0 * PI / (double)MR;
    const double dif = (double)(MR - HALFN) * (MR - HALFN) - (double)HALFN * HALFN;
    const double tau = (4.0 * gam) / (2.0 * sqrt(dif));        // P=4 balance
    const double alpha = gam * gam / (4.0 * tau);
    const double L2E = 1.4426950408889634;
    const float nalpha = (float)(-alpha * L2E);                // exp2 scale
    const float sfac   = (float)(gam / sqrt(4.0 * PI * tau));
    const float taul2e = (float)(tau * L2E);

    int nb = (int)(ws_size / 65536) - 1;   // 64 KB per partial grid + 64 KB for G
    if (nb > NBMAX) nb = NBMAX;
    if (nb < 1)     nb = 1;
    int ppb = (M + nb - 1) / nb;

    hipLaunchKernelGGL(nufft_spread, dim3(nb), dim3(STPB), 0, stream,
                       pts, vre, vim, ws, M, ppb, nalpha);
    hipLaunchKernelGGL(nufft_reduce_grid, dim3(128), dim3(128), 0, stream, ws, nb);
    hipLaunchKernelGGL(nufft_fft, dim3(1), dim3(1024), 0, stream,
                       ws, out, out_size, sfac, taul2e);
}

// Round 8
// 60.029 us; speedup vs baseline: 72.9834x; 2.6096x over previous
//
#include <hip/hip_runtime.h>
#include <math.h>

#define NM    4096          // output modes
#define HALFN 2048
#define MR    8192          // oversampled grid (2x)
#define MRM   (MR - 1)
#define STPB  512           // spread threads per block
#define NB    256           // partial grids (257*64KB = 16.8 MB of ws)
#define FSCALE 65536.0f     // fixed-point scale 2^16
#define INVFS  (1.0f / 65536.0f)

// hw trig: v_sin_f32/v_cos_f32 take REVOLUTIONS (sin/cos of 2*pi*r). Verified round 5.
__device__ __forceinline__ float sin2pi(float r) {
    float o; asm volatile("v_sin_f32 %0, %1" : "=v"(o) : "v"(r)); return o;
}
__device__ __forceinline__ float cos2pi(float r) {
    float o; asm volatile("v_cos_f32 %0, %1" : "=v"(o) : "v"(r)); return o;
}

// ---------------- 1) spread: points -> privatized LDS int grid -> ws partials
// b_m = sum_j c_j * exp(-alpha*(m - p_j)^2), 8-wide Gaussian, fixed-point 2^16.
// atomicAdd(int) on LDS is native ds_add_u32 (no CAS loop, bit-deterministic).
// ws layout (floats): [0,16384) = reduced grid G (re|im planar),
//                     [16384 + b*16384, ...) = block b's partial grid (float).
__global__ __launch_bounds__(STPB) void nufft_spread(
    const float* __restrict__ pts, const float* __restrict__ vre,
    const float* __restrict__ vim, float* __restrict__ ws,
    int M, int ppb, float nalpha)
{
    __shared__ int gre[MR];
    __shared__ int gim[MR];
    const int tid = threadIdx.x;
    const int b   = blockIdx.x;

    for (int i = tid; i < MR; i += STPB) { gre[i] = 0; gim[i] = 0; }
    __syncthreads();

    const int j0   = b * ppb;
    const int jend = min(j0 + ppb, M);
    const float inv2pi = 0.15915494309189535f;

    for (int j = j0 + tid; j < jend; j += STPB) {
        float x  = pts[j];
        float cr = vre[j] * FSCALE;
        float ci = vim[j] * FSCALE;
        float u = x * inv2pi;
        u -= floorf(u);                 // [0,1)
        float p  = u * (float)MR;       // grid position [0, 8192]
        float fl = floorf(p);
        int   i0 = (int)fl - 3;
        float d  = fl - p - 3.0f;       // m - p for m = i0, in (-4, -3]
#pragma unroll
        for (int i = 0; i < 8; ++i) {
            float wgt = exp2f(nalpha * d * d);    // exp(-alpha*d^2)
            int m = (i0 + i) & MRM;
            atomicAdd(&gre[m], (int)(wgt * cr));  // ds_add_u32, native
            atomicAdd(&gim[m], (int)(wgt * ci));
            d += 1.0f;
        }
    }
    __syncthreads();

    // writeback: int -> float, planar re|im
    float* buf = ws + 16384 + (size_t)b * 16384;
    for (int i = tid; i < MR; i += STPB) {
        buf[i]      = (float)gre[i] * INVFS;
        buf[MR + i] = (float)gim[i] * INVFS;
    }
}

// ---------------- 2) reduce partial grids -> G ------------------------------
// 128 blocks x 128 threads = 16384: one float column per thread, coalesced.
__global__ __launch_bounds__(128) void nufft_reduce_grid(
    float* __restrict__ ws, int nb)
{
    int i = blockIdx.x * 128 + threadIdx.x;          // [0, 16384)
    const float* src = ws + 16384 + i;
    float s = 0.f;
#pragma unroll 8
    for (int b = 0; b < nb; ++b) s += src[(size_t)b * 16384];
    ws[i] = s;   // [0,16384) never aliases the read region
}

// ---------------- 3) single-block 8192-pt FFT (+i sign) + deconv + output ---
// B_k = sum_m b_m e^{+2pi i k m / MR};  f[k] = B_k * sfac * e^{k^2 tau}.
__global__ __launch_bounds__(1024) void nufft_fft(
    const float* __restrict__ ws, float* __restrict__ out,
    int out_size, float sfac, float taul2e)
{
    __shared__ float re[MR];
    __shared__ float im[MR];
    const int tid = threadIdx.x;

    // load with bit-reversal (13-bit)
    for (int q = tid; q < MR; q += 1024) {
        int r = __brev((unsigned)q) >> 19;
        re[r] = ws[q];
        im[r] = ws[MR + q];
    }
    __syncthreads();

    for (int half = 1; half < MR; half <<= 1) {
        int len = half << 1;
        float sc = 1.0f / (float)len;
        for (int q = tid; q < MR / 2; q += 1024) {
            int t  = q & (half - 1);
            int i0 = ((q - t) << 1) + t;             // (q/half)*len + t
            float tf = (float)t * sc;                // t/len in [0, 0.5)
            float wr = cos2pi(tf);
            float wi = sin2pi(tf);                   // e^{+2pi i t/len}
            float ur = re[i0],        ui = im[i0];
            float xr = re[i0 + half], xi = im[i0 + half];
            float vr = fmaf(xr, wr, -(xi * wi));
            float vi = fmaf(xr, wi,   xi * wr);
            re[i0]        = ur + vr;  im[i0]        = ui + vi;
            re[i0 + half] = ur - vr;  im[i0 + half] = ui - vi;
        }
        __syncthreads();
    }

    // deconvolve + write planar (or real-only) FFT-ordered modes
    for (int idx = tid; idx < NM; idx += 1024) {
        int k    = (idx < HALFN) ? idx : idx - NM;
        int src  = (idx < HALFN) ? idx : idx + NM;   // k mod 8192
        float kk = (float)k;
        float corr = sfac * exp2f(kk * kk * taul2e); // sfac * e^{k^2 tau}
        float fre = re[src] * corr;
        float fim = im[src] * corr;
        if (out_size >= 2 * NM) {
            out[idx]      = fre;
            out[NM + idx] = fim;
        } else {
            out[idx] = fre;
        }
    }
}

extern "C" void kernel_launch(void* const* d_in, const int* in_sizes, int n_in,
                              void* d_out, int out_size, void* d_ws, size_t ws_size,
                              hipStream_t stream)
{
    const float* pts = (const float*)d_in[0];
    const float* vre = (const float*)d_in[1];
    const float* vim = (const float*)d_in[2];
    float* out = (float*)d_out;
    float* ws  = (float*)d_ws;
    const int M = in_sizes[0];

    // Gaussian kernel parameters (double-derived, balanced truncation/aliasing)
    const double PI  = 3.14159265358979323846;
    const double gam = 2.0 * PI / (double)MR;
    const double dif = (double)(MR - HALFN) * (MR - HALFN) - (double)HALFN * HALFN;
    const double tau = (4.0 * gam) / (2.0 * sqrt(dif));        // P=4 balance
    const double alpha = gam * gam / (4.0 * tau);
    const double L2E = 1.4426950408889634;
    const float nalpha = (float)(-alpha * L2E);                // exp2 scale
    const float sfac   = (float)(gam / sqrt(4.0 * PI * tau));
    const float taul2e = (float)(tau * L2E);

    int nb = NB;
    while (nb > 1 && (size_t)(nb + 1) * 65536 > ws_size) nb >>= 1;
    int ppb = (M + nb - 1) / nb;

    hipLaunchKernelGGL(nufft_spread, dim3(nb), dim3(STPB), 0, stream,
                       pts, vre, vim, ws, M, ppb, nalpha);
    hipLaunchKernelGGL(nufft_reduce_grid, dim3(128), dim3(128), 0, stream, ws, nb);
    hipLaunchKernelGGL(nufft_fft, dim3(1), dim3(1024), 0, stream,
                       ws, out, out_size, sfac, taul2e);
}

// Round 9
// 37.606 us; speedup vs baseline: 116.4993x; 1.5962x over previous
//
#include <hip/hip_runtime.h>
#include <math.h>

#define NM    4096          // output modes
#define HALFN 2048
#define MR    8192          // oversampled grid (2x)
#define MRM   (MR - 1)
#define STPB  512           // spread threads per block
#define NB    256           // partial grids
#define FSCALE 65536.0f     // fixed-point scale 2^16
#define INVFS  (1.0f / 65536.0f)
#define PAD(i) ((i) + ((i) >> 5))   // LDS bank-conflict padding

// hw trig/exp: v_sin/v_cos take REVOLUTIONS; v_exp_f32 computes 2^x.
__device__ __forceinline__ float sin2pi(float r) {
    float o; asm volatile("v_sin_f32 %0, %1" : "=v"(o) : "v"(r)); return o;
}
__device__ __forceinline__ float cos2pi(float r) {
    float o; asm volatile("v_cos_f32 %0, %1" : "=v"(o) : "v"(r)); return o;
}
__device__ __forceinline__ float exp2a(float x) {
    float o; asm volatile("v_exp_f32 %0, %1" : "=v"(o) : "v"(x)); return o;
}

// ---------------- 1) spread: points -> privatized LDS int grid -> int partials
// wgt_i = exp(-alpha*(t0+i)^2) = E1 * r^i * C[i]  (2 exps/point, 2 muls/tap).
// ws layout: [0,16384) floats = reduced grid G (re|im planar);
//            ints at [16384 + b*16384, ...) = block b's partial grid (int).
__global__ __launch_bounds__(STPB) void nufft_spread(
    const float* __restrict__ pts, const float* __restrict__ vre,
    const float* __restrict__ vim, float* __restrict__ ws,
    int M, int ppb, float nalpha, float4 cA, float4 cB)
{
    __shared__ int gre[MR];
    __shared__ int gim[MR];
    const int tid = threadIdx.x;
    const int b   = blockIdx.x;
    const float C[8] = {cA.x, cA.y, cA.z, cA.w, cB.x, cB.y, cB.z, cB.w};

    for (int i = tid; i < MR; i += STPB) { gre[i] = 0; gim[i] = 0; }
    __syncthreads();

    const int j0   = b * ppb;
    const int jend = min(j0 + ppb, M);
    const float inv2pi = 0.15915494309189535f;

    for (int j = j0 + tid; j < jend; j += STPB) {
        float x  = pts[j];
        float cr = vre[j];
        float ci = vim[j];
        float u = x * inv2pi;
        u -= floorf(u);                 // [0,1)
        float p  = u * (float)MR;       // grid position [0, 8192]
        float fl = floorf(p);
        int   i0 = (int)fl - 3;
        float t0 = (fl - p) - 3.0f;     // m - p for m = i0, in (-4, -3]
        float E1 = exp2a(nalpha * t0 * t0);      // exp(-alpha*t0^2)
        float r  = exp2a(2.0f * nalpha * t0);    // exp(-2*alpha*t0) in [28, 85]
        float crs = cr * (FSCALE)*E1;
        float cis = ci * (FSCALE)*E1;
        float w = 1.0f;
#pragma unroll
        for (int i = 0; i < 8; ++i) {
            float wgt = w * C[i];
            int m = (i0 + i) & MRM;
            atomicAdd(&gre[m], (int)(wgt * crs));   // native ds_add_u32
            atomicAdd(&gim[m], (int)(wgt * cis));
            w *= r;
        }
    }
    __syncthreads();

    // raw int writeback, vectorized
    int4* buf = (int4*)((int*)ws + 16384 + (size_t)b * 16384);
    const int4* g4r = (const int4*)gre;
    const int4* g4i = (const int4*)gim;
    for (int i = tid; i < MR / 4; i += STPB) {
        buf[i]          = g4r[i];
        buf[MR / 4 + i] = g4i[i];
    }
}

// ---------------- 2) reduce int partials -> float grid G --------------------
// 128 blocks x 128 threads: one column per thread, coalesced; exact int sums.
__global__ __launch_bounds__(128) void nufft_reduce_grid(
    float* __restrict__ ws, int nb)
{
    int i = blockIdx.x * 128 + threadIdx.x;          // [0, 16384)
    const int* src = (const int*)ws + 16384 + i;
    int s = 0;
#pragma unroll 8
    for (int b = 0; b < nb; ++b) s += src[(size_t)b * 16384];
    ws[i] = (float)s * INVFS;   // [0,16384) never aliases the read region
}

// ---------------- 3) single-block 8192-pt DIF FFT (+i) + deconv + output ----
// radix-2 stage then 6 radix-4 stages, natural input, digit-reversed output;
// deconv resolves the digit reversal at read time. LDS padded (i + i/32).
__global__ __launch_bounds__(1024) void nufft_fft(
    const float* __restrict__ ws, float* __restrict__ out,
    int out_size, float sfac, float taul2e)
{
    __shared__ float re[MR + MR / 32];
    __shared__ float im[MR + MR / 32];
    const int tid = threadIdx.x;

    for (int q = tid; q < MR; q += 1024) {
        re[PAD(q)] = ws[q];
        im[PAD(q)] = ws[MR + q];
    }
    __syncthreads();

    // radix-2 DIF: y0 = a+b (k even half), y1 = (a-b)*w^t (k odd half)
    for (int t = tid; t < MR / 2; t += 1024) {
        int ia = PAD(t), ib = PAD(t + MR / 2);
        float ar = re[ia], ai = im[ia];
        float br = re[ib], bi = im[ib];
        re[ia] = ar + br;  im[ia] = ai + bi;
        float dr = ar - br, di = ai - bi;
        float tf = (float)t * (1.0f / (float)MR);
        float wr = cos2pi(tf), wi = sin2pi(tf);      // e^{+2pi i t/8192}
        re[ib] = fmaf(dr, wr, -(di * wi));
        im[ib] = fmaf(dr, wi,   di * wr);
    }
    __syncthreads();

    // radix-4 DIF stages: span h = 1024,256,64,16,4,1  (L = 4h)
    for (int lh = 10; lh >= 0; lh -= 2) {
        int h = 1 << lh;
        float invL = 1.0f / (float)(h << 2);
        for (int idx = tid; idx < MR / 4; idx += 1024) {
            int t    = idx & (h - 1);
            int base = ((idx >> lh) << (lh + 2)) + t;
            int ia = PAD(base), ib = PAD(base + h), ic = PAD(base + 2 * h), id = PAD(base + 3 * h);
            float ar = re[ia], ai = im[ia];
            float br = re[ib], bi = im[ib];
            float cr = re[ic], ci = im[ic];
            float dr = re[id], di = im[id];
            float er = ar + cr, ei = ai + ci;        // a + c
            float fr = ar - cr, fi = ai - ci;        // a - c
            float gr = br + dr, gi = bi + di;        // b + d
            float hr = br - dr, hi = bi - di;        // b - d
            // y0 = e+g ; y1 = (f + i*h)*w ; y2 = (e-g)*w^2 ; y3 = (f - i*h)*w^3
            float y1r = fr - hi, y1i = fi + hr;
            float y2r = er - gr, y2i = ei - gi;
            float y3r = fr + hi, y3i = fi - hr;
            float tf  = (float)t * invL;             // < 0.25
            float w1r = cos2pi(tf),        w1i = sin2pi(tf);
            float w2r = cos2pi(2.0f * tf), w2i = sin2pi(2.0f * tf);
            float w3r = cos2pi(3.0f * tf), w3i = sin2pi(3.0f * tf);
            re[ia] = er + gr;  im[ia] = ei + gi;
            re[ib] = fmaf(y1r, w1r, -(y1i * w1i));
            im[ib] = fmaf(y1r, w1i,   y1i * w1r);
            re[ic] = fmaf(y2r, w2r, -(y2i * w2i));
            im[ic] = fmaf(y2r, w2i,   y2i * w2r);
            re[id] = fmaf(y3r, w3r, -(y3i * w3i));
            im[id] = fmaf(y3r, w3i,   y3i * w3r);
        }
        __syncthreads();
    }

    // deconvolve + write planar modes; storage index = digit-reversal of k8
    for (int idx = tid; idx < NM; idx += 1024) {
        int k   = (idx < HALFN) ? idx : idx - NM;
        int k8  = (idx < HALFN) ? idx : idx + NM;    // k mod 8192
        int s0 = k8 & 1, v = k8 >> 1;
        int p = (s0 << 12) | ((v & 3) << 10) | (((v >> 2) & 3) << 8)
              | (((v >> 4) & 3) << 6) | (((v >> 6) & 3) << 4)
              | (((v >> 8) & 3) << 2) | ((v >> 10) & 3);
        float kk = (float)k;
        float corr = sfac * exp2a(kk * kk * taul2e); // sfac * e^{k^2 tau}
        float fre = re[PAD(p)] * corr;
        float fim = im[PAD(p)] * corr;
        if (out_size >= 2 * NM) {
            out[idx]      = fre;
            out[NM + idx] = fim;
        } else {
            out[idx] = fre;
        }
    }
}

extern "C" void kernel_launch(void* const* d_in, const int* in_sizes, int n_in,
                              void* d_out, int out_size, void* d_ws, size_t ws_size,
                              hipStream_t stream)
{
    const float* pts = (const float*)d_in[0];
    const float* vre = (const float*)d_in[1];
    const float* vim = (const float*)d_in[2];
    float* out = (float*)d_out;
    float* ws  = (float*)d_ws;
    const int M = in_sizes[0];

    // Gaussian kernel: alpha = pi*sqrt(2)/8 (P=4 balanced, E = 16*alpha = 8.886)
    const double PI  = 3.14159265358979323846;
    const double gam = 2.0 * PI / (double)MR;
    const double alpha = PI * sqrt(2.0) / 8.0;
    const double tau = gam * gam / (4.0 * alpha);
    const double L2E = 1.4426950408889634;
    const float nalpha = (float)(-alpha * L2E);                // exp2 scale
    const float sfac   = (float)(gam / sqrt(4.0 * PI * tau));
    const float taul2e = (float)(tau * L2E);
    float4 cA = make_float4(1.0f, (float)exp(-alpha), (float)exp(-alpha * 4.0),
                            (float)exp(-alpha * 9.0));
    float4 cB = make_float4((float)exp(-alpha * 16.0), (float)exp(-alpha * 25.0),
                            (float)exp(-alpha * 36.0), (float)exp(-alpha * 49.0));

    int nb = NB;
    while (nb > 1 && (size_t)(nb + 1) * 65536 > ws_size) nb >>= 1;
    int ppb = (M + nb - 1) / nb;

    hipLaunchKernelGGL(nufft_spread, dim3(nb), dim3(STPB), 0, stream,
                       pts, vre, vim, ws, M, ppb, nalpha, cA, cB);
    hipLaunchKernelGGL(nufft_reduce_grid, dim3(128), dim3(128), 0, stream, ws, nb);
    hipLaunchKernelGGL(nufft_fft, dim3(1), dim3(1024), 0, stream,
                       ws, out, out_size, sfac, taul2e);
}

// Round 10
// 35.585 us; speedup vs baseline: 123.1159x; 1.0568x over previous
//
#include <hip/hip_runtime.h>
#include <math.h>

#define NM    4096          // output modes
#define HALFN 2048
#define MR    8192          // oversampled grid (2x)
#define MRM   (MR - 1)
#define STPB  512           // spread threads per block
#define NB    256           // partial grids
#define W     6             // Gaussian taps (E = 6.66, err ~1.3e-3 rel)
#define FSCALE 65536.0f     // fixed-point scale 2^16
#define INVFS  (1.0f / 65536.0f)
#define PAD(i) ((i) + ((i) >> 5))   // LDS bank-conflict padding

// hw trig/exp: v_sin/v_cos take REVOLUTIONS; v_exp_f32 computes 2^x.
__device__ __forceinline__ float sin2pi(float r) {
    float o; asm volatile("v_sin_f32 %0, %1" : "=v"(o) : "v"(r)); return o;
}
__device__ __forceinline__ float cos2pi(float r) {
    float o; asm volatile("v_cos_f32 %0, %1" : "=v"(o) : "v"(r)); return o;
}
__device__ __forceinline__ float exp2a(float x) {
    float o; asm volatile("v_exp_f32 %0, %1" : "=v"(o) : "v"(x)); return o;
}

// ---------------- 1) spread: points -> privatized LDS int grid -> int partials
// wgt_i = exp(-alpha*(t0+i)^2) = E1 * r^i * C[i]  (2 exps/point, 2 muls/tap).
// ws layout: [0,16384) floats = reduced grid G (re|im planar);
//            ints at [16384 + b*16384, ...) = block b's partial grid (int).
__global__ __launch_bounds__(STPB) void nufft_spread(
    const float* __restrict__ pts, const float* __restrict__ vre,
    const float* __restrict__ vim, float* __restrict__ ws,
    int M, int ppb, float nalpha, float4 cA, float2 cB)
{
    __shared__ int gre[MR];
    __shared__ int gim[MR];
    const int tid = threadIdx.x;
    const int b   = blockIdx.x;
    const float C[W] = {cA.x, cA.y, cA.z, cA.w, cB.x, cB.y};

    for (int i = tid; i < MR; i += STPB) { gre[i] = 0; gim[i] = 0; }
    __syncthreads();

    const int j0   = b * ppb;
    const int jend = min(j0 + ppb, M);
    const float inv2pi = 0.15915494309189535f;

    for (int j = j0 + tid; j < jend; j += STPB) {
        float x  = pts[j];
        float cr = vre[j];
        float ci = vim[j];
        float u = x * inv2pi;
        u -= floorf(u);                 // [0,1)
        float p  = u * (float)MR;       // grid position [0, 8192]
        float fl = floorf(p);
        int   i0 = (int)fl - 2;
        float t0 = (fl - p) - 2.0f;     // m - p for m = i0, in (-3, -2]
        float E1 = exp2a(nalpha * t0 * t0);      // exp(-alpha*t0^2)
        float r  = exp2a(2.0f * nalpha * t0);    // exp(-2*alpha*t0), ~[19, 86]
        float crs = cr * FSCALE * E1;
        float cis = ci * FSCALE * E1;
        float w = 1.0f;
#pragma unroll
        for (int i = 0; i < W; ++i) {
            float wgt = w * C[i];
            int m = (i0 + i) & MRM;
            atomicAdd(&gre[m], (int)(wgt * crs));   // native ds_add_u32
            atomicAdd(&gim[m], (int)(wgt * cis));
            w *= r;
        }
    }
    __syncthreads();

    // raw int writeback, vectorized
    int4* buf = (int4*)((int*)ws + 16384 + (size_t)b * 16384);
    const int4* g4r = (const int4*)gre;
    const int4* g4i = (const int4*)gim;
    for (int i = tid; i < MR / 4; i += STPB) {
        buf[i]          = g4r[i];
        buf[MR / 4 + i] = g4i[i];
    }
}

// ---------------- 2) reduce int partials -> float grid G --------------------
// 256 blocks x 64 threads = 16384: one column per thread, coalesced, all CUs.
__global__ __launch_bounds__(64) void nufft_reduce_grid(
    float* __restrict__ ws, int nb)
{
    int i = blockIdx.x * 64 + threadIdx.x;           // [0, 16384)
    const int* src = (const int*)ws + 16384 + i;
    int s = 0;
#pragma unroll 8
    for (int b = 0; b < nb; ++b) s += src[(size_t)b * 16384];
    ws[i] = (float)s * INVFS;   // [0,16384) never aliases the read region
}

// ---------------- 3) single-block 8192-pt DIF FFT (+i) + deconv + output ----
// radix-2 stage then 6 radix-4 stages, natural input, digit-reversed output;
// deconv resolves the digit reversal at read time. LDS padded (i + i/32).
__global__ __launch_bounds__(1024) void nufft_fft(
    const float* __restrict__ ws, float* __restrict__ out,
    int out_size, float sfac, float taul2e)
{
    __shared__ float re[MR + MR / 32];
    __shared__ float im[MR + MR / 32];
    const int tid = threadIdx.x;

    for (int q = tid; q < MR; q += 1024) {
        re[PAD(q)] = ws[q];
        im[PAD(q)] = ws[MR + q];
    }
    __syncthreads();

    // radix-2 DIF: y0 = a+b (k even half), y1 = (a-b)*w^t (k odd half)
    for (int t = tid; t < MR / 2; t += 1024) {
        int ia = PAD(t), ib = PAD(t + MR / 2);
        float ar = re[ia], ai = im[ia];
        float br = re[ib], bi = im[ib];
        re[ia] = ar + br;  im[ia] = ai + bi;
        float dr = ar - br, di = ai - bi;
        float tf = (float)t * (1.0f / (float)MR);
        float wr = cos2pi(tf), wi = sin2pi(tf);      // e^{+2pi i t/8192}
        re[ib] = fmaf(dr, wr, -(di * wi));
        im[ib] = fmaf(dr, wi,   di * wr);
    }
    __syncthreads();

    // radix-4 DIF stages: span h = 1024,256,64,16,4,1  (L = 4h)
    for (int lh = 10; lh >= 0; lh -= 2) {
        int h = 1 << lh;
        float invL = 1.0f / (float)(h << 2);
        for (int idx = tid; idx < MR / 4; idx += 1024) {
            int t    = idx & (h - 1);
            int base = ((idx >> lh) << (lh + 2)) + t;
            int ia = PAD(base), ib = PAD(base + h), ic = PAD(base + 2 * h), id = PAD(base + 3 * h);
            float ar = re[ia], ai = im[ia];
            float br = re[ib], bi = im[ib];
            float cr = re[ic], ci = im[ic];
            float dr = re[id], di = im[id];
            float er = ar + cr, ei = ai + ci;        // a + c
            float fr = ar - cr, fi = ai - ci;        // a - c
            float gr = br + dr, gi = bi + di;        // b + d
            float hr = br - dr, hi = bi - di;        // b - d
            // y0 = e+g ; y1 = (f + i*h)*w ; y2 = (e-g)*w^2 ; y3 = (f - i*h)*w^3
            float y1r = fr - hi, y1i = fi + hr;
            float y2r = er - gr, y2i = ei - gi;
            float y3r = fr + hi, y3i = fi - hr;
            float tf  = (float)t * invL;             // < 0.25
            float w1r = cos2pi(tf),        w1i = sin2pi(tf);
            float w2r = cos2pi(2.0f * tf), w2i = sin2pi(2.0f * tf);
            float w3r = cos2pi(3.0f * tf), w3i = sin2pi(3.0f * tf);
            re[ia] = er + gr;  im[ia] = ei + gi;
            re[ib] = fmaf(y1r, w1r, -(y1i * w1i));
            im[ib] = fmaf(y1r, w1i,   y1i * w1r);
            re[ic] = fmaf(y2r, w2r, -(y2i * w2i));
            im[ic] = fmaf(y2r, w2i,   y2i * w2r);
            re[id] = fmaf(y3r, w3r, -(y3i * w3i));
            im[id] = fmaf(y3r, w3i,   y3i * w3r);
        }
        __syncthreads();
    }

    // deconvolve + write planar modes; storage index = digit-reversal of k8
    for (int idx = tid; idx < NM; idx += 1024) {
        int k   = (idx < HALFN) ? idx : idx - NM;
        int k8  = (idx < HALFN) ? idx : idx + NM;    // k mod 8192
        int s0 = k8 & 1, v = k8 >> 1;
        int p = (s0 << 12) | ((v & 3) << 10) | (((v >> 2) & 3) << 8)
              | (((v >> 4) & 3) << 6) | (((v >> 6) & 3) << 4)
              | (((v >> 8) & 3) << 2) | ((v >> 10) & 3);
        float kk = (float)k;
        float corr = sfac * exp2a(kk * kk * taul2e); // sfac * e^{k^2 tau}
        float fre = re[PAD(p)] * corr;
        float fim = im[PAD(p)] * corr;
        if (out_size >= 2 * NM) {
            out[idx]      = fre;
            out[NM + idx] = fim;
        } else {
            out[idx] = fre;
        }
    }
}

extern "C" void kernel_launch(void* const* d_in, const int* in_sizes, int n_in,
                              void* d_out, int out_size, void* d_ws, size_t ws_size,
                              hipStream_t stream)
{
    const float* pts = (const float*)d_in[0];
    const float* vre = (const float*)d_in[1];
    const float* vim = (const float*)d_in[2];
    float* out = (float*)d_out;
    float* ws  = (float*)d_ws;
    const int M = in_sizes[0];

    // Gaussian kernel, w=6, balanced: alpha = gam*sqrt(dif)/6, E = 9*alpha = 6.66
    const double PI  = 3.14159265358979323846;
    const double gam = 2.0 * PI / (double)MR;
    const double dif = (double)(MR - HALFN) * (MR - HALFN) - (double)HALFN * HALFN;
    const double alpha = gam * sqrt(dif) / 6.0;
    const double tau = gam * gam / (4.0 * alpha);
    const double L2E = 1.4426950408889634;
    const float nalpha = (float)(-alpha * L2E);                // exp2 scale
    const float sfac   = (float)sqrt(alpha / PI);
    const float taul2e = (float)(tau * L2E);
    float4 cA = make_float4(1.0f, (float)exp(-alpha), (float)exp(-alpha * 4.0),
                            (float)exp(-alpha * 9.0));
    float2 cB = make_float2((float)exp(-alpha * 16.0), (float)exp(-alpha * 25.0));

    int nb = NB;
    while (nb > 1 && (size_t)(nb + 1) * 65536 > ws_size) nb >>= 1;
    int ppb = (M + nb - 1) / nb;

    hipLaunchKernelGGL(nufft_spread, dim3(nb), dim3(STPB), 0, stream,
                       pts, vre, vim, ws, M, ppb, nalpha, cA, cB);
    hipLaunchKernelGGL(nufft_reduce_grid, dim3(256), dim3(64), 0, stream, ws, nb);
    hipLaunchKernelGGL(nufft_fft, dim3(1), dim3(1024), 0, stream,
                       ws, out, out_size, sfac, taul2e);
}